// Round 13
// baseline (424.428 us; speedup 1.0000x reference)
//
#include <hip/hip_runtime.h>

#define NPTS 12288
#define LQPAD 1800
#define LPAD2 1856
#define EPSBN 1e-4f
#define NSPLIT 8
#define LOG2E 1.44269504088896340736f

#if __has_builtin(__builtin_amdgcn_exp2f)
#define EXP2F __builtin_amdgcn_exp2f
#else
#define EXP2F exp2f
#endif

typedef _Float16 half8 __attribute__((ext_vector_type(8)));
typedef _Float16 half4 __attribute__((ext_vector_type(4)));
typedef float floatx4 __attribute__((ext_vector_type(4)));

// ---------------- pack ALL weights + compute Wpq (g==1) + count_valid (g>=97) -------------
__global__ __launch_bounds__(256) void pack_all(const float* Wp1, const float* Wq, const float* Wk,
                                                const float* Wv, const float* Wt_, const float* Wq1,
                                                const float* Wk1, const float* Wv1, const float* Wdown,
                                                const float* W3t, const float* W3a, const float* W3b,
                                                const int* __restrict__ pad_idx, int* __restrict__ counts,
                                                _Float16* __restrict__ Wf) {
    int g = blockIdx.x;
    int t = threadIdx.x;
    if (g >= 97) {
        int b = g - 97;
        int s = 0;
        for (int i = t; i < LQPAD; i += 256) s += (pad_idx[b * LQPAD + i] >= 0) ? 1 : 0;
        for (int off = 32; off > 0; off >>= 1) s += __shfl_xor(s, off);
        if ((t & 63) == 0) atomicAdd(&counts[b], s);
        return;
    }
    int lane = t & 63, fg = t >> 6;
    int quad = lane >> 4, qi = lane & 15;
    if (g == 1) {
        __shared__ float A[4096], Bs[4096];
        for (int i = t; i < 4096; i += 256) {
            A[i] = Wp1[i];
            Bs[i] = Wq[i];
        }
        __syncthreads();
#pragma unroll
        for (int u = 0; u < 2; u++) {
            int frag = fg * 2 + u;
            int s = frag >> 2, ct = frag & 3;
            half8 v;
#pragma unroll
            for (int j = 0; j < 8; j++) {
                int r = s * 32 + quad * 8 + j, c = ct * 16 + qi;
                float acc = 0.f;
#pragma unroll
                for (int k = 0; k < 64; k++) acc += A[r * 64 + k] * Bs[k * 64 + c];
                v[j] = (_Float16)acc;
            }
            *(half8*)(Wf + (size_t)4096 + frag * 512 + lane * 8) = v;
        }
        return;
    }
    const float* src;
    if (g == 0) src = Wp1;
    else if (g == 2) src = Wk;
    else if (g == 3) src = Wv;
    else if (g == 4) src = Wt_;
    else if (g == 5) src = Wq1;
    else if (g == 6) src = Wk1;
    else if (g == 7) src = Wv1;
    else if (g < 16) src = Wdown + (size_t)(g - 8) * 4096;
    else if (g < 43) src = W3t + (size_t)(g - 16) * 4096;
    else if (g < 70) src = W3a + (size_t)(g - 43) * 4096;
    else src = W3b + (size_t)(g - 70) * 4096;
#pragma unroll
    for (int u = 0; u < 2; u++) {
        int frag = fg * 2 + u;
        int s = frag >> 2, ct = frag & 3;
        half8 v;
#pragma unroll
        for (int j = 0; j < 8; j++) v[j] = (_Float16)src[(s * 32 + quad * 8 + j) * 64 + ct * 16 + qi];
        *(half8*)(Wf + (size_t)g * 4096 + frag * 512 + lane * 8) = v;
    }
}

// A fp32 row -> hi/lo half8 fragments
__device__ inline void load_split8(const float* p, half8& hi, half8& lo) {
    float4 a = *(const float4*)p;
    float4 b = *(const float4*)(p + 4);
    float v[8] = {a.x, a.y, a.z, a.w, b.x, b.y, b.z, b.w};
#pragma unroll
    for (int j = 0; j < 8; j++) {
        _Float16 h = (_Float16)v[j];
        hi[j] = h;
        lo[j] = (_Float16)(v[j] - (float)h);
    }
}

// ---------------- gemm_head: 4 GEMMs in one launch (stage-1 inputs) ----------------
__global__ __launch_bounds__(256) void gemm_head(const float* __restrict__ xdec, const float* __restrict__ xenc,
                                                 const _Float16* __restrict__ Wf, float* __restrict__ xd,
                                                 _Float16* __restrict__ Qh,
                                                 _Float16* __restrict__ Kh, _Float16* __restrict__ Vt) {
    int z = blockIdx.y;
    const float* A = (z < 2) ? xdec : xenc;
    const _Float16* Bf = Wf + (size_t)z * 4096;
    int t = threadIdx.x;
    int lane = t & 63, wv = t >> 6;
    int quad = lane >> 4, qi = lane & 15;
    int row0w = blockIdx.x * 64 + wv * 16;
    half8 ah[2], al[2];
#pragma unroll
    for (int s = 0; s < 2; s++) load_split8(A + (size_t)(row0w + qi) * 64 + s * 32 + quad * 8, ah[s], al[s]);
    floatx4 C[4];
#pragma unroll
    for (int ct = 0; ct < 4; ct++) C[ct] = floatx4{0.f, 0.f, 0.f, 0.f};
#pragma unroll
    for (int ct = 0; ct < 4; ct++)
#pragma unroll
        for (int s = 0; s < 2; s++) {
            half8 b = *(const half8*)(Bf + (s * 4 + ct) * 512 + lane * 8);
            C[ct] = __builtin_amdgcn_mfma_f32_16x16x32_f16(ah[s], b, C[ct], 0, 0, 0);
            C[ct] = __builtin_amdgcn_mfma_f32_16x16x32_f16(al[s], b, C[ct], 0, 0, 0);
        }
    int orow = row0w + quad * 4;
    if (z == 0) {
#pragma unroll
        for (int ct = 0; ct < 4; ct++)
#pragma unroll
            for (int r = 0; r < 4; r++) xd[(size_t)(orow + r) * 64 + ct * 16 + qi] = C[ct][r];
    } else if (z == 1) {
#pragma unroll
        for (int ct = 0; ct < 4; ct++)
#pragma unroll
            for (int r = 0; r < 4; r++)
                Qh[(size_t)(orow + r) * 64 + ct * 16 + qi] = (_Float16)(C[ct][r] * LOG2E);
    } else if (z == 2) {
#pragma unroll
        for (int ct = 0; ct < 4; ct++)
#pragma unroll
            for (int r = 0; r < 4; r++) Kh[(size_t)(orow + r) * 64 + ct * 16 + qi] = (_Float16)C[ct][r];
    } else {
#pragma unroll
        for (int ct = 0; ct < 4; ct++) {
            half4 o;
#pragma unroll
            for (int r = 0; r < 4; r++) o[r] = (_Float16)C[ct][r];
            *(half4*)(Vt + (size_t)(ct * 16 + qi) * NPTS + orow) = o;
        }
    }
}

// ---------------- gemm_q1: fused [xd += BN(xr)] prologue + q1 = xd@Wq1 (fp16 out) ---------
__global__ __launch_bounds__(256) void gemm_q1(const float* __restrict__ xr, float* __restrict__ xd,
                                               const _Float16* __restrict__ Bf,
                                               const float* __restrict__ stats,
                                               const float* __restrict__ gamma,
                                               const float* __restrict__ beta,
                                               _Float16* __restrict__ Oh) {
    int t = threadIdx.x;
    int lane = t & 63, wv = t >> 6;
    int quad = lane >> 4, qi = lane & 15;
    int row0w = blockIdx.x * 64 + wv * 16;
    const float inv_n = 1.f / (float)NPTS;
    half8 ah[2], al[2];
#pragma unroll
    for (int s = 0; s < 2; s++) {
        size_t base = (size_t)(row0w + qi) * 64 + s * 32 + quad * 8;
        float4 xa = *(const float4*)(xr + base);
        float4 xb = *(const float4*)(xr + base + 4);
        float4 da = *(const float4*)(xd + base);
        float4 db = *(const float4*)(xd + base + 4);
        float vx[8] = {xa.x, xa.y, xa.z, xa.w, xb.x, xb.y, xb.z, xb.w};
        float vd[8] = {da.x, da.y, da.z, da.w, db.x, db.y, db.z, db.w};
        float vo[8];
#pragma unroll
        for (int j = 0; j < 8; j++) {
            int f = s * 32 + quad * 8 + j;
            float mean = stats[f] * inv_n;
            float var = stats[64 + f] * inv_n - mean * mean;
            float val = vd[j] + (vx[j] - mean) * rsqrtf(var + EPSBN) * gamma[f] + beta[f];
            vo[j] = val;
            _Float16 h = (_Float16)val;
            ah[s][j] = h;
            al[s][j] = (_Float16)(val - (float)h);
        }
        *(float4*)(xd + base) = float4{vo[0], vo[1], vo[2], vo[3]};
        *(float4*)(xd + base + 4) = float4{vo[4], vo[5], vo[6], vo[7]};
    }
    floatx4 C[4];
#pragma unroll
    for (int ct = 0; ct < 4; ct++) C[ct] = floatx4{0.f, 0.f, 0.f, 0.f};
#pragma unroll
    for (int ct = 0; ct < 4; ct++)
#pragma unroll
        for (int s = 0; s < 2; s++) {
            half8 b = *(const half8*)(Bf + (s * 4 + ct) * 512 + lane * 8);
            C[ct] = __builtin_amdgcn_mfma_f32_16x16x32_f16(ah[s], b, C[ct], 0, 0, 0);
            C[ct] = __builtin_amdgcn_mfma_f32_16x16x32_f16(al[s], b, C[ct], 0, 0, 0);
        }
    int orow = row0w + quad * 4;
#pragma unroll
    for (int ct = 0; ct < 4; ct++)
#pragma unroll
        for (int r = 0; r < 4; r++) Oh[(size_t)(orow + r) * 64 + ct * 16 + qi] = (_Float16)C[ct][r];
}

// ---------------- gemm_kv1: BN(kv) fused prologue; y=0 -> Kh1, y=1 -> Vt2 scatter ---------
__global__ __launch_bounds__(256) void gemm_kv1(const float* __restrict__ kv, const _Float16* __restrict__ Wfk,
                                                const _Float16* __restrict__ Wfv,
                                                const float* __restrict__ stats, const float* __restrict__ gamma,
                                                const float* __restrict__ beta, const int* __restrict__ unpad,
                                                _Float16* __restrict__ Kh1, _Float16* __restrict__ Vt2) {
    int y = blockIdx.y;
    int t = threadIdx.x;
    int lane = t & 63, wv = t >> 6;
    int quad = lane >> 4, qi = lane & 15;
    int row0w = blockIdx.x * 64 + wv * 16;
    const float inv_n = 1.f / (float)NPTS;
    half8 ah[2], al[2];
#pragma unroll
    for (int s = 0; s < 2; s++) {
        const float* p = kv + (size_t)(row0w + qi) * 64 + s * 32 + quad * 8;
        float4 a = *(const float4*)p;
        float4 b2 = *(const float4*)(p + 4);
        float v[8] = {a.x, a.y, a.z, a.w, b2.x, b2.y, b2.z, b2.w};
#pragma unroll
        for (int j = 0; j < 8; j++) {
            int f = s * 32 + quad * 8 + j;
            float mean = stats[f] * inv_n;
            float var = stats[64 + f] * inv_n - mean * mean;
            float val = (v[j] - mean) * rsqrtf(var + EPSBN) * gamma[f] + beta[f];
            _Float16 h = (_Float16)val;
            ah[s][j] = h;
            al[s][j] = (_Float16)(val - (float)h);
        }
    }
    const _Float16* Bf = y ? Wfv : Wfk;
    floatx4 C[4];
#pragma unroll
    for (int ct = 0; ct < 4; ct++) C[ct] = floatx4{0.f, 0.f, 0.f, 0.f};
#pragma unroll
    for (int ct = 0; ct < 4; ct++)
#pragma unroll
        for (int s = 0; s < 2; s++) {
            half8 b = *(const half8*)(Bf + (s * 4 + ct) * 512 + lane * 8);
            C[ct] = __builtin_amdgcn_mfma_f32_16x16x32_f16(ah[s], b, C[ct], 0, 0, 0);
            C[ct] = __builtin_amdgcn_mfma_f32_16x16x32_f16(al[s], b, C[ct], 0, 0, 0);
        }
    int orow = row0w + quad * 4;
    if (y == 0) {
#pragma unroll
        for (int ct = 0; ct < 4; ct++)
#pragma unroll
            for (int r = 0; r < 4; r++) Kh1[(size_t)(orow + r) * 64 + ct * 16 + qi] = (_Float16)C[ct][r];
    } else {
        int u0 = unpad[orow], u3 = unpad[orow + 3];
        int b0 = u0 / 1800, b3 = u3 / 1800;
        if (u3 == u0 + 3 && b0 == b3) {
            int p0 = u0 - b0 * 1800;
#pragma unroll
            for (int ct = 0; ct < 4; ct++) {
                half4 o;
#pragma unroll
                for (int r = 0; r < 4; r++) o[r] = (_Float16)C[ct][r];
                *(half4*)(Vt2 + ((size_t)b0 * 64 + ct * 16 + qi) * LPAD2 + p0) = o;
            }
        } else {
#pragma unroll
            for (int r = 0; r < 4; r++) {
                int u = unpad[orow + r];
                int b = u / 1800, p = u - b * 1800;
#pragma unroll
                for (int ct = 0; ct < 4; ct++)
                    Vt2[((size_t)b * 64 + ct * 16 + qi) * LPAD2 + p] = (_Float16)C[ct][r];
            }
        }
    }
}

// ---------------- gather conv, MFMA, f-split (fsplit in {2,4}), depth-1 pipeline ----------
__global__ __launch_bounds__(256) void gconv_mfma(const _Float16* __restrict__ Xh,
                                                  const int* __restrict__ idx,
                                                  const _Float16* __restrict__ Wf,
                                                  float* __restrict__ OUT, int nk, int fsplit,
                                                  const float* Xadd, float* stats_out) {
    __shared__ float s_sum[64], s_ss[64];
    int t = threadIdx.x;
    int lane = t & 63, wv = t >> 6;
    int quad = lane >> 4, qi = lane & 15;
    int bx = blockIdx.x;
    int nct = 4 / fsplit;                       // ct tiles per block
    int row0 = (bx / fsplit) * 64 + wv * 16;
    int cb = (bx % fsplit) * nct;
    if (stats_out) {
        if (t < 64) {
            s_sum[t] = 0.f;
            s_ss[t] = 0.f;
        }
        __syncthreads();
    }
    floatx4 Oacc[2];
#pragma unroll
    for (int u = 0; u < 2; u++) Oacc[u] = floatx4{0.f, 0.f, 0.f, 0.f};
    const int* ip = idx + (size_t)(row0 + qi) * nk;
    int j = ip[0];
    half8 a0 = half8{0, 0, 0, 0, 0, 0, 0, 0};
    half8 a1 = half8{0, 0, 0, 0, 0, 0, 0, 0};
    if (j >= 0) {
        a0 = *(const half8*)(Xh + (size_t)j * 64 + quad * 8);
        a1 = *(const half8*)(Xh + (size_t)j * 64 + 32 + quad * 8);
    }
    for (int k = 0; k < nk; k++) {
        half8 n0 = half8{0, 0, 0, 0, 0, 0, 0, 0};
        half8 n1 = half8{0, 0, 0, 0, 0, 0, 0, 0};
        if (k + 1 < nk) {
            int jn = ip[k + 1];
            if (jn >= 0) {
                n0 = *(const half8*)(Xh + (size_t)jn * 64 + quad * 8);
                n1 = *(const half8*)(Xh + (size_t)jn * 64 + 32 + quad * 8);
            }
        }
        const _Float16* wk = Wf + (size_t)k * 4096;
        for (int u = 0; u < nct; u++) {
            int ct = cb + u;
            half8 b0 = *(const half8*)(wk + ct * 512 + lane * 8);
            half8 b1 = *(const half8*)(wk + (4 + ct) * 512 + lane * 8);
            Oacc[u] = __builtin_amdgcn_mfma_f32_16x16x32_f16(a0, b0, Oacc[u], 0, 0, 0);
            Oacc[u] = __builtin_amdgcn_mfma_f32_16x16x32_f16(a1, b1, Oacc[u], 0, 0, 0);
        }
        a0 = n0;
        a1 = n1;
    }
    int orow = row0 + quad * 4;
    for (int u = 0; u < nct; u++) {
        int ct = cb + u;
#pragma unroll
        for (int r = 0; r < 4; r++) OUT[(size_t)(orow + r) * 64 + ct * 16 + qi] = Oacc[u][r];
    }
    if (stats_out) {
        for (int u = 0; u < nct; u++) {
            int f = (cb + u) * 16 + qi;
            float ps = 0.f, pss = 0.f;
#pragma unroll
            for (int r = 0; r < 4; r++) {
                float v = Oacc[u][r];
                if (Xadd) v += Xadd[(size_t)(orow + r) * 64 + f];
                ps += v;
                pss += v * v;
            }
            atomicAdd(&s_sum[f], ps);
            atomicAdd(&s_ss[f], pss);
        }
        __syncthreads();
        if (t < 64) {
            atomicAdd(&stats_out[t], s_sum[t]);
            atomicAdd(&stats_out[64 + t], s_ss[t]);
        }
    }
}

// ---------------- gather conv with fused BN+ReLU prologue, f-split x4 ----------------
__global__ __launch_bounds__(256) void gconv_bn_mfma(const float* __restrict__ X,
                                                     const int* __restrict__ idx,
                                                     const _Float16* __restrict__ Wf,
                                                     float* __restrict__ OUT, int nk,
                                                     const float* __restrict__ stats,
                                                     const float* __restrict__ gamma,
                                                     const float* __restrict__ beta,
                                                     const float* Xadd, float* stats_out) {
    __shared__ float s_sum[64], s_ss[64];
    int t = threadIdx.x;
    int lane = t & 63, wv = t >> 6;
    int quad = lane >> 4, qi = lane & 15;
    int bx = blockIdx.x;
    int row0 = (bx >> 2) * 64 + wv * 16;
    int ct = bx & 3;
    if (t < 64) {
        s_sum[t] = 0.f;
        s_ss[t] = 0.f;
    }
    __syncthreads();
    const float inv_n = 1.f / (float)NPTS;
    float sc[2][8], sh[2][8];
#pragma unroll
    for (int s = 0; s < 2; s++)
#pragma unroll
        for (int jj = 0; jj < 8; jj++) {
            int f = s * 32 + quad * 8 + jj;
            float mean = stats[f] * inv_n;
            float var = stats[64 + f] * inv_n - mean * mean;
            float rs = rsqrtf(var + EPSBN) * gamma[f];
            sc[s][jj] = rs;
            sh[s][jj] = beta[f] - mean * rs;
        }
    floatx4 Oacc = floatx4{0.f, 0.f, 0.f, 0.f};
    const int* ip = idx + (size_t)(row0 + qi) * nk;
    float cur[16];
    int jvalid;
    {
        int j0 = ip[0];
        jvalid = (j0 >= 0);
        if (jvalid) {
            const float* p = X + (size_t)j0 * 64 + quad * 8;
            float4 x0 = *(const float4*)p;
            float4 x1 = *(const float4*)(p + 4);
            float4 x2 = *(const float4*)(p + 32);
            float4 x3 = *(const float4*)(p + 36);
            cur[0] = x0.x; cur[1] = x0.y; cur[2] = x0.z; cur[3] = x0.w;
            cur[4] = x1.x; cur[5] = x1.y; cur[6] = x1.z; cur[7] = x1.w;
            cur[8] = x2.x; cur[9] = x2.y; cur[10] = x2.z; cur[11] = x2.w;
            cur[12] = x3.x; cur[13] = x3.y; cur[14] = x3.z; cur[15] = x3.w;
        }
    }
    for (int k = 0; k < nk; k++) {
        half8 a0, a1;
        if (jvalid) {
#pragma unroll
            for (int e = 0; e < 8; e++) {
                a0[e] = (_Float16)fmaxf(cur[e] * sc[0][e] + sh[0][e], 0.f);
                a1[e] = (_Float16)fmaxf(cur[8 + e] * sc[1][e] + sh[1][e], 0.f);
            }
        } else {
            a0 = half8{0, 0, 0, 0, 0, 0, 0, 0};
            a1 = half8{0, 0, 0, 0, 0, 0, 0, 0};
        }
        int nvalid = 0;
        float nxt[16];
        if (k + 1 < nk) {
            int jn = ip[k + 1];
            nvalid = (jn >= 0);
            if (nvalid) {
                const float* p = X + (size_t)jn * 64 + quad * 8;
                float4 x0 = *(const float4*)p;
                float4 x1 = *(const float4*)(p + 4);
                float4 x2 = *(const float4*)(p + 32);
                float4 x3 = *(const float4*)(p + 36);
                nxt[0] = x0.x; nxt[1] = x0.y; nxt[2] = x0.z; nxt[3] = x0.w;
                nxt[4] = x1.x; nxt[5] = x1.y; nxt[6] = x1.z; nxt[7] = x1.w;
                nxt[8] = x2.x; nxt[9] = x2.y; nxt[10] = x2.z; nxt[11] = x2.w;
                nxt[12] = x3.x; nxt[13] = x3.y; nxt[14] = x3.z; nxt[15] = x3.w;
            }
        }
        const _Float16* wk = Wf + (size_t)k * 4096;
        half8 b0 = *(const half8*)(wk + ct * 512 + lane * 8);
        half8 b1 = *(const half8*)(wk + (4 + ct) * 512 + lane * 8);
        Oacc = __builtin_amdgcn_mfma_f32_16x16x32_f16(a0, b0, Oacc, 0, 0, 0);
        Oacc = __builtin_amdgcn_mfma_f32_16x16x32_f16(a1, b1, Oacc, 0, 0, 0);
        jvalid = nvalid;
#pragma unroll
        for (int e = 0; e < 16; e++) cur[e] = nxt[e];
    }
    int orow = row0 + quad * 4;
#pragma unroll
    for (int r = 0; r < 4; r++) OUT[(size_t)(orow + r) * 64 + ct * 16 + qi] = Oacc[r];
    {
        int f = ct * 16 + qi;
        float ps = 0.f, pss = 0.f;
#pragma unroll
        for (int r = 0; r < 4; r++) {
            float v = Oacc[r];
            if (Xadd) v += Xadd[(size_t)(orow + r) * 64 + f];
            ps += v;
            pss += v * v;
        }
        atomicAdd(&s_sum[f], ps);
        atomicAdd(&s_ss[f], pss);
    }
    __syncthreads();
    if (t < 64) {
        atomicAdd(&stats_out[t], s_sum[t]);
        atomicAdd(&stats_out[64 + t], s_ss[t]);
    }
}

// ---------------- bn_apply ----------------
__global__ __launch_bounds__(256) void bn_apply(const float* __restrict__ X, const float* X2,
                                                const float* R, float* OUT, _Float16* OUT16,
                                                const float* __restrict__ stats,
                                                const float* __restrict__ gamma,
                                                const float* __restrict__ beta,
                                                float* stats_out, int n, int do_relu) {
    __shared__ float sh[2][4][64];
    int t = threadIdx.x;
    int f = t & 63, g = t >> 6;
    float inv_n = 1.f / (float)n;
    float mean = stats[f] * inv_n;
    float var = stats[64 + f] * inv_n - mean * mean;
    float rstd = rsqrtf(var + EPSBN);
    float ga = gamma[f], be = beta[f];
    float s = 0.f, ss = 0.f;
    for (int r = blockIdx.x * 4 + g; r < n; r += gridDim.x * 4) {
        size_t i = (size_t)r * 64 + f;
        float v = X[i];
        if (X2) v += X2[i];
        v = (v - mean) * rstd * ga + be;
        if (R) v += R[i];
        if (do_relu) v = fmaxf(v, 0.f);
        if (OUT) OUT[i] = v;
        if (OUT16) OUT16[i] = (_Float16)v;
        s += v;
        ss += v * v;
    }
    if (stats_out) {
        sh[0][g][f] = s;
        sh[1][g][f] = ss;
        __syncthreads();
        if (g == 0) {
            s = sh[0][0][f] + sh[0][1][f] + sh[0][2][f] + sh[0][3][f];
            ss = sh[1][0][f] + sh[1][1][f] + sh[1][2][f] + sh[1][3][f];
            atomicAdd(&stats_out[f], s);
            atomicAdd(&stats_out[64 + f], ss);
        }
    }
}

// ---------------- Stage-1 flash attention: log2-domain softmax, alpha-skip ----------------
__global__ __launch_bounds__(256, 3) void flash1_mfma(const _Float16* __restrict__ Qh,
                                                      const _Float16* __restrict__ Kh,
                                                      const _Float16* __restrict__ Vt,
                                                      _Float16* __restrict__ Op,
                                                      float* __restrict__ Ms,
                                                      float* __restrict__ Ls) {
    __shared__ __align__(16) _Float16 KsF[8 * 512];
    __shared__ __align__(16) _Float16 VsF[8 * 512];
    __shared__ __align__(16) _Float16 PTF[4][2 * 1024];
    int t = threadIdx.x;
    int lane = t & 63, wv = t >> 6;
    int quad = lane >> 4, qi = lane & 15;
    int qb = blockIdx.x, sp = blockIdx.y;
    int q0w = qb * 128 + wv * 32;

    half8 qh[2][2];
#pragma unroll
    for (int sub = 0; sub < 2; sub++)
#pragma unroll
        for (int s = 0; s < 2; s++) {
            int qrow = q0w + sub * 16 + qi;
            qh[sub][s] = *(const half8*)(Qh + (size_t)qrow * 64 + s * 32 + quad * 8);
        }
    floatx4 Oacc[2][4];
#pragma unroll
    for (int sub = 0; sub < 2; sub++)
#pragma unroll
        for (int ft = 0; ft < 4; ft++) Oacc[sub][ft] = floatx4{0.f, 0.f, 0.f, 0.f};
    float m_i[2] = {-1e30f, -1e30f}, l_i[2] = {0.f, 0.f};

    for (int it = 0; it < 24; it++) {
        int k0 = sp * 1536 + it * 64;
        __syncthreads();
#pragma unroll
        for (int u = 0; u < 4; u++) {
            int frag = wv + 4 * u;
            if (frag < 8) {
                int kt = frag >> 1, s = frag & 1;
                int key = k0 + kt * 16 + qi;
                *(half8*)(KsF + frag * 512 + lane * 8) =
                    *(const half8*)(Kh + (size_t)key * 64 + s * 32 + quad * 8);
            } else {
                int fr = frag - 8;
                int ft = fr >> 1, s = fr & 1;
                int f = ft * 16 + qi;
                *(half8*)(VsF + fr * 512 + lane * 8) =
                    *(const half8*)(Vt + (size_t)f * NPTS + k0 + s * 32 + quad * 8);
            }
        }
        __syncthreads();
        half8 ka[4][2];
#pragma unroll
        for (int kt = 0; kt < 4; kt++)
#pragma unroll
            for (int s = 0; s < 2; s++) ka[kt][s] = *(const half8*)(KsF + (kt * 2 + s) * 512 + lane * 8);
        floatx4 st[2][4];
#pragma unroll
        for (int sub = 0; sub < 2; sub++)
#pragma unroll
            for (int kt = 0; kt < 4; kt++) {
                floatx4 acc = floatx4{0.f, 0.f, 0.f, 0.f};
#pragma unroll
                for (int s = 0; s < 2; s++)
                    acc = __builtin_amdgcn_mfma_f32_16x16x32_f16(ka[kt][s], qh[sub][s], acc, 0, 0, 0);
                st[sub][kt] = acc;
            }
#pragma unroll
        for (int sub = 0; sub < 2; sub++) {
            float mloc = -1e30f;
#pragma unroll
            for (int kt = 0; kt < 4; kt++)
#pragma unroll
                for (int r = 0; r < 4; r++) mloc = fmaxf(mloc, st[sub][kt][r]);
            mloc = fmaxf(mloc, __shfl_xor(mloc, 16));
            mloc = fmaxf(mloc, __shfl_xor(mloc, 32));
            float m_new = fmaxf(m_i[sub], mloc);
            float ps = 0.f;
#pragma unroll
            for (int kt = 0; kt < 4; kt++) {
                half4 pk;
#pragma unroll
                for (int r = 0; r < 4; r++) {
                    float p = EXP2F(st[sub][kt][r] - m_new);
                    ps += p;
                    pk[r] = (_Float16)p;
                }
                int s = kt >> 1;
                int qd2 = (kt & 1) * 2 + (quad >> 1);
                *(half4*)(&PTF[wv][sub * 1024 + (s * 64 + qd2 * 16 + qi) * 8 + (quad & 1) * 4]) = pk;
            }
            ps += __shfl_xor(ps, 16);
            ps += __shfl_xor(ps, 32);
            if (m_new > m_i[sub]) {
                float alpha = EXP2F(m_i[sub] - m_new);
                l_i[sub] = l_i[sub] * alpha + ps;
                m_i[sub] = m_new;
#pragma unroll
                for (int ft = 0; ft < 4; ft++) Oacc[sub][ft] *= alpha;
            } else {
                l_i[sub] += ps;
            }
        }
        half8 pb[2][2];
#pragma unroll
        for (int sub = 0; sub < 2; sub++)
#pragma unroll
            for (int s = 0; s < 2; s++)
                pb[sub][s] = *(const half8*)(&PTF[wv][sub * 1024 + (s * 64 + lane) * 8]);
#pragma unroll
        for (int ft = 0; ft < 4; ft++)
#pragma unroll
            for (int s = 0; s < 2; s++) {
                half8 v = *(const half8*)(VsF + (ft * 2 + s) * 512 + lane * 8);
                Oacc[0][ft] = __builtin_amdgcn_mfma_f32_16x16x32_f16(v, pb[0][s], Oacc[0][ft], 0, 0, 0);
                Oacc[1][ft] = __builtin_amdgcn_mfma_f32_16x16x32_f16(v, pb[1][s], Oacc[1][ft], 0, 0, 0);
            }
    }
#pragma unroll
    for (int sub = 0; sub < 2; sub++) {
#pragma unroll
        for (int ft = 0; ft < 4; ft++) {
            half4 o;
#pragma unroll
            for (int r = 0; r < 4; r++) o[r] = (_Float16)Oacc[sub][ft][r];
            *(half4*)(Op + ((size_t)sp * NPTS + q0w + sub * 16 + qi) * 64 + ft * 16 + quad * 4) = o;
        }
        if (lane < 16) {
            Ms[sp * NPTS + q0w + sub * 16 + lane] = m_i[sub];
            Ls[sp * NPTS + q0w + sub * 16 + lane] = l_i[sub];
        }
    }
}

// ---------------- merge NSPLIT partials (log2-domain m) + @Wt + fused BN-stats ------------
__global__ __launch_bounds__(256) void merge_gemm(const _Float16* __restrict__ Op,
                                                  const float* __restrict__ Ms, const float* __restrict__ Ls,
                                                  const _Float16* __restrict__ Wtf,
                                                  float* __restrict__ xr, float* __restrict__ stats_out) {
    __shared__ float w12[64][NSPLIT];
    __shared__ float Linv[64];
    __shared__ __align__(16) _Float16 Ah[64 * 72], Al[64 * 72];
    __shared__ float s_sum[64], s_ss[64];
    int t = threadIdx.x;
    int row0 = blockIdx.x * 64;
    if (t < 64) {
        int q = row0 + t;
        float m[NSPLIT], M = -1e30f;
#pragma unroll
        for (int s = 0; s < NSPLIT; s++) {
            m[s] = Ms[s * NPTS + q];
            M = fmaxf(M, m[s]);
        }
        float L = 0.f;
#pragma unroll
        for (int s = 0; s < NSPLIT; s++) {
            float w = EXP2F(m[s] - M);
            w12[t][s] = w;
            L += Ls[s * NPTS + q] * w;
        }
        Linv[t] = 1.f / L;
        s_sum[t] = 0.f;
        s_ss[t] = 0.f;
    }
    __syncthreads();
    for (int k = 0; k < 4; k++) {
        int i = t + k * 256;
        int qr = i >> 4, f4 = (i & 15) * 4;
        int q = row0 + qr;
        float acc[4] = {0.f, 0.f, 0.f, 0.f};
#pragma unroll
        for (int s = 0; s < NSPLIT; s++) {
            float w = w12[qr][s];
            half4 o = *(const half4*)(Op + ((size_t)s * NPTS + q) * 64 + f4);
#pragma unroll
            for (int c = 0; c < 4; c++) acc[c] += (float)o[c] * w;
        }
        float inv = Linv[qr];
#pragma unroll
        for (int c = 0; c < 4; c++) {
            float val = acc[c] * inv;
            _Float16 h = (_Float16)val;
            Ah[qr * 72 + f4 + c] = h;
            Al[qr * 72 + f4 + c] = (_Float16)(val - (float)h);
        }
    }
    __syncthreads();
    int lane = t & 63, wv = t >> 6;
    int quad = lane >> 4, qi = lane & 15;
    int rloc = wv * 16 + qi;
    half8 ah[2], al[2];
#pragma unroll
    for (int s = 0; s < 2; s++) {
        ah[s] = *(const half8*)(Ah + rloc * 72 + s * 32 + quad * 8);
        al[s] = *(const half8*)(Al + rloc * 72 + s * 32 + quad * 8);
    }
    floatx4 C[4];
#pragma unroll
    for (int ct = 0; ct < 4; ct++) C[ct] = floatx4{0.f, 0.f, 0.f, 0.f};
#pragma unroll
    for (int ct = 0; ct < 4; ct++)
#pragma unroll
        for (int s = 0; s < 2; s++) {
            half8 b = *(const half8*)(Wtf + (s * 4 + ct) * 512 + lane * 8);
            C[ct] = __builtin_amdgcn_mfma_f32_16x16x32_f16(ah[s], b, C[ct], 0, 0, 0);
            C[ct] = __builtin_amdgcn_mfma_f32_16x16x32_f16(al[s], b, C[ct], 0, 0, 0);
        }
    int orow = row0 + wv * 16 + quad * 4;
#pragma unroll
    for (int ct = 0; ct < 4; ct++) {
        int f = ct * 16 + qi;
        float ps = 0.f, pss = 0.f;
#pragma unroll
        for (int r = 0; r < 4; r++) {
            float v = C[ct][r];
            xr[(size_t)(orow + r) * 64 + f] = v;
            ps += v;
            pss += v * v;
        }
        atomicAdd(&s_sum[f], ps);
        atomicAdd(&s_ss[f], pss);
    }
    __syncthreads();
    if (t < 64) {
        atomicAdd(&stats_out[t], s_sum[t]);
        atomicAdd(&stats_out[64 + t], s_ss[t]);
    }
}

// ---------------- Stage-2 ragged flash attention, fp16 Q (linear domain), alpha-skip ------
__global__ __launch_bounds__(256) void flash2_mfma(const _Float16* __restrict__ Qh,
                                                   const _Float16* __restrict__ Kh,
                                                   const _Float16* __restrict__ Vt2,
                                                   const int* __restrict__ pad_idx,
                                                   const int* __restrict__ counts,
                                                   _Float16* __restrict__ O) {
    int b = blockIdx.y;
    int c = counts[b];
    int qb = blockIdx.x;
    if (qb * 64 >= c) return;
    __shared__ __align__(16) _Float16 KsF[8 * 512];
    __shared__ __align__(16) _Float16 VsF[8 * 512];
    __shared__ __align__(16) _Float16 PTF[4][2 * 512];
    int t = threadIdx.x;
    int lane = t & 63, wv = t >> 6;
    int quad = lane >> 4, qi = lane & 15;
    const int* prow = pad_idx + b * LQPAD;
    int p_q = qb * 64 + wv * 16 + qi;
    int flat_q = (p_q < LQPAD) ? prow[p_q] : -1;

    half8 qh[2];
#pragma unroll
    for (int s = 0; s < 2; s++) {
        qh[s] = (flat_q >= 0) ? *(const half8*)(Qh + (size_t)flat_q * 64 + s * 32 + quad * 8)
                              : half8{0, 0, 0, 0, 0, 0, 0, 0};
    }
    floatx4 Oacc[4];
#pragma unroll
    for (int ft = 0; ft < 4; ft++) Oacc[ft] = floatx4{0.f, 0.f, 0.f, 0.f};
    float m_i = -1e30f, l_i = 0.f;
    const _Float16* VtB = Vt2 + (size_t)b * 64 * LPAD2;

    int nt = (c + 63) >> 6;
    for (int it = 0; it < nt; it++) {
        int k0 = it * 64;
        __syncthreads();
#pragma unroll
        for (int u = 0; u < 4; u++) {
            int frag = wv + 4 * u;
            if (frag < 8) {
                int kt = frag >> 1, s = frag & 1;
                int kp = k0 + kt * 16 + qi;
                int flat = (kp < c) ? prow[kp] : -1;
                int d0 = s * 32 + quad * 8;
                half8 kvv = half8{0, 0, 0, 0, 0, 0, 0, 0};
                if (flat >= 0) kvv = *(const half8*)(Kh + (size_t)flat * 64 + d0);
                *(half8*)(KsF + frag * 512 + lane * 8) = kvv;
            } else {
                int fr = frag - 8;
                int ft = fr >> 1, s = fr & 1;
                int f = ft * 16 + qi;
                int key = k0 + s * 32 + quad * 8;
                *(half8*)(VsF + fr * 512 + lane * 8) = *(const half8*)(VtB + f * LPAD2 + key);
            }
        }
        __syncthreads();
        floatx4 st[4];
#pragma unroll
        for (int kt = 0; kt < 4; kt++) {
            floatx4 acc = floatx4{0.f, 0.f, 0.f, 0.f};
#pragma unroll
            for (int s = 0; s < 2; s++) {
                half8 a = *(const half8*)(KsF + (kt * 2 + s) * 512 + lane * 8);
                acc = __builtin_amdgcn_mfma_f32_16x16x32_f16(a, qh[s], acc, 0, 0, 0);
            }
            st[kt] = acc;
        }
        float mloc = -1e30f;
#pragma unroll
        for (int kt = 0; kt < 4; kt++)
#pragma unroll
            for (int r = 0; r < 4; r++) mloc = fmaxf(mloc, st[kt][r]);
        mloc = fmaxf(mloc, __shfl_xor(mloc, 16));
        mloc = fmaxf(mloc, __shfl_xor(mloc, 32));
        float m_new = fmaxf(m_i, mloc);
        float ps = 0.f;
#pragma unroll
        for (int kt = 0; kt < 4; kt++) {
            half4 pk;
#pragma unroll
            for (int r = 0; r < 4; r++) {
                int kpos = k0 + kt * 16 + quad * 4 + r;
                float p = (kpos < c) ? __expf(st[kt][r] - m_new) : 0.f;
                ps += p;
                pk[r] = (_Float16)p;
            }
            int s = kt >> 1;
            int qd2 = (kt & 1) * 2 + (quad >> 1);
            *(half4*)(&PTF[wv][(s * 64 + qd2 * 16 + qi) * 8 + (quad & 1) * 4]) = pk;
        }
        ps += __shfl_xor(ps, 16);
        ps += __shfl_xor(ps, 32);
        if (m_new > m_i) {
            float alpha = __expf(m_i - m_new);
            l_i = l_i * alpha + ps;
            m_i = m_new;
#pragma unroll
            for (int ft = 0; ft < 4; ft++) Oacc[ft] *= alpha;
        } else {
            l_i += ps;
        }
        half8 pb[2];
#pragma unroll
        for (int s = 0; s < 2; s++) pb[s] = *(const half8*)(&PTF[wv][(s * 64 + lane) * 8]);
#pragma unroll
        for (int ft = 0; ft < 4; ft++)
#pragma unroll
            for (int s = 0; s < 2; s++) {
                half8 a = *(const half8*)(VsF + (ft * 2 + s) * 512 + lane * 8);
                Oacc[ft] = __builtin_amdgcn_mfma_f32_16x16x32_f16(a, pb[s], Oacc[ft], 0, 0, 0);
            }
    }
    if (flat_q >= 0) {
        float inv = 1.f / l_i;
#pragma unroll
        for (int ft = 0; ft < 4; ft++) {
            half4 o;
#pragma unroll
            for (int r = 0; r < 4; r++) o[r] = (_Float16)(Oacc[ft][r] * inv);
            *(half4*)(O + (size_t)flat_q * 64 + ft * 16 + quad * 4) = o;
        }
    }
}

extern "C" void kernel_launch(void* const* d_in, const int* in_sizes, int n_in,
                              void* d_out, int out_size, void* d_ws, size_t ws_size,
                              hipStream_t stream) {
    const float* x_dec = (const float*)d_in[0];
    const float* x_enc = (const float*)d_in[1];
    const float* Wp1 = (const float*)d_in[2];
    const float* Wq = (const float*)d_in[3];
    const float* Wk = (const float*)d_in[4];
    const float* Wv = (const float*)d_in[5];
    const float* Wt_ = (const float*)d_in[6];
    const float* Wq1 = (const float*)d_in[7];
    const float* Wk1 = (const float*)d_in[8];
    const float* Wv1 = (const float*)d_in[9];
    const float* Wdown = (const float*)d_in[10];
    const float* W3t = (const float*)d_in[11];
    const float* W3a = (const float*)d_in[12];
    const float* W3b = (const float*)d_in[13];
    const float* bn_g = (const float*)d_in[14];
    const float* bn_b = (const float*)d_in[15];
    const int* nbr = (const int*)d_in[16];
    const int* kv_nbr = (const int*)d_in[17];
    const int* pad_idx = (const int*)d_in[18];
    const int* unpad_idx = (const int*)d_in[19];
    float* out = (float*)d_out;
    float* ws = (float*)d_ws;

    const int N = NPTS;
    const size_t BUF = (size_t)N * 64;
    float* xd = ws;
    float* s1 = ws + 1 * BUF;
    float* s2 = ws + 2 * BUF;
    float* s3 = ws + 3 * BUF;
    float* s4 = ws + 4 * BUF;
    float* s5 = ws + 5 * BUF;
    float* s7 = ws + 7 * BUF;
    float* s8 = ws + 8 * BUF;
    float* arena = ws + 9 * BUF;

    float* stats = arena;
    int* counts = (int*)(arena + 768);
    float* Ms = arena + 1024;
    float* Ls = Ms + (size_t)NSPLIT * NPTS;
    _Float16* WfA = (_Float16*)(Ls + (size_t)NSPLIT * NPTS);

    _Float16* Oph = (_Float16*)s1;              // 8 partials: s1..s4
    _Float16* Qh = (_Float16*)s7;
    _Float16* Kh = (_Float16*)s8;
    _Float16* Vt = Kh + BUF;
    float* xr = s8;                             // after flash1 (Kh/Vt dead)
    _Float16* Qh1 = (_Float16*)s7;
    float* kv = s1;
    _Float16* Kh1 = (_Float16*)s2;
    _Float16* Vt2 = (_Float16*)s3;
    _Float16* z2h = (_Float16*)s4;
    float* xr2 = s5;
    float* o2 = s1;                             // res-block: W3a out
    float* z2 = s3;                             // W3b out

    const _Float16* Wtf = WfA + 4 * 4096;
    const _Float16* Wq1f = WfA + 5 * 4096;
    const _Float16* Wk1f = WfA + 6 * 4096;
    const _Float16* Wv1f = WfA + 7 * 4096;
    const _Float16* Wdf = WfA + 8 * 4096;
    const _Float16* W3tf = WfA + (size_t)16 * 4096;
    const _Float16* W3af = WfA + (size_t)43 * 4096;
    const _Float16* W3bf = WfA + (size_t)70 * 4096;

    hipMemsetAsync(stats, 0, 1024 * sizeof(float), stream);

    dim3 B(256);
    int gG = N / 64;      // 192
    int gC2 = 2 * gG;     // 384: f-split x2 (8-tap conv)
    int gC4 = 4 * gG;     // 768: f-split x4 (27-tap convs)

    pack_all<<<105, B, 0, stream>>>(Wp1, Wq, Wk, Wv, Wt_, Wq1, Wk1, Wv1, Wdown, W3t, W3a, W3b,
                                    pad_idx, counts, WfA);

    gemm_head<<<dim3(gG, 4), B, 0, stream>>>(x_dec, x_enc, WfA, xd, Qh, Kh, Vt);
    flash1_mfma<<<dim3(N / 128, NSPLIT), B, 0, stream>>>(Qh, Kh, Vt, Oph, Ms, Ls);
    merge_gemm<<<gG, B, 0, stream>>>(Oph, Ms, Ls, Wtf, xr, stats + 0);
    gemm_q1<<<gG, B, 0, stream>>>(xr, xd, Wq1f, stats + 0, bn_g + 0, bn_b + 0, Qh1);

    gconv_mfma<<<gC2, B, 0, stream>>>(Qh1, kv_nbr, Wdf, kv, 8, 2, nullptr, stats + 128);
    gemm_kv1<<<dim3(gG, 2), B, 0, stream>>>(kv, Wk1f, Wv1f, stats + 128, bn_g + 64, bn_b + 64,
                                            unpad_idx, Kh1, Vt2);
    flash2_mfma<<<dim3(LPAD2 / 64, 8), B, 0, stream>>>(Qh1, Kh1, Vt2, pad_idx, counts, z2h);
    gconv_mfma<<<gC4, B, 0, stream>>>(z2h, nbr, W3tf, xr2, 27, 4, nullptr, stats + 256);
    bn_apply<<<256, B, 0, stream>>>(xr2, nullptr, xd, xd, nullptr, stats + 256, bn_g + 128, bn_b + 128,
                                    stats + 384, N, 0);

    gconv_bn_mfma<<<gC4, B, 0, stream>>>(xd, nbr, W3af, o2, 27, stats + 384, bn_g + 192, bn_b + 192,
                                         nullptr, stats + 512);
    gconv_bn_mfma<<<gC4, B, 0, stream>>>(o2, nbr, W3bf, z2, 27, stats + 512, bn_g + 256, bn_b + 256,
                                         xd, stats + 640);
    bn_apply<<<256, B, 0, stream>>>(xd, z2, nullptr, out, nullptr, stats + 640, bn_g + 320, bn_b + 320,
                                    nullptr, N, 1);
}

// Round 14
// 397.982 us; speedup vs baseline: 1.0664x; 1.0664x over previous
//
#include <hip/hip_runtime.h>

#define NPTS 12288
#define LQPAD 1800
#define LPAD2 1856
#define EPSBN 1e-4f
#define NSPLIT 8
#define LOG2E 1.44269504088896340736f

#if __has_builtin(__builtin_amdgcn_exp2f)
#define EXP2F __builtin_amdgcn_exp2f
#else
#define EXP2F exp2f
#endif

typedef _Float16 half8 __attribute__((ext_vector_type(8)));
typedef _Float16 half4 __attribute__((ext_vector_type(4)));
typedef float floatx4 __attribute__((ext_vector_type(4)));

// ---------------- pack ALL weights + compute Wpq (g==1) + count_valid (g>=97) -------------
__global__ __launch_bounds__(256) void pack_all(const float* Wp1, const float* Wq, const float* Wk,
                                                const float* Wv, const float* Wt_, const float* Wq1,
                                                const float* Wk1, const float* Wv1, const float* Wdown,
                                                const float* W3t, const float* W3a, const float* W3b,
                                                const int* __restrict__ pad_idx, int* __restrict__ counts,
                                                _Float16* __restrict__ Wf) {
    int g = blockIdx.x;
    int t = threadIdx.x;
    if (g >= 97) {
        int b = g - 97;
        int s = 0;
        for (int i = t; i < LQPAD; i += 256) s += (pad_idx[b * LQPAD + i] >= 0) ? 1 : 0;
        for (int off = 32; off > 0; off >>= 1) s += __shfl_xor(s, off);
        if ((t & 63) == 0) atomicAdd(&counts[b], s);
        return;
    }
    int lane = t & 63, fg = t >> 6;
    int quad = lane >> 4, qi = lane & 15;
    if (g == 1) {
        __shared__ float A[4096], Bs[4096];
        for (int i = t; i < 4096; i += 256) {
            A[i] = Wp1[i];
            Bs[i] = Wq[i];
        }
        __syncthreads();
#pragma unroll
        for (int u = 0; u < 2; u++) {
            int frag = fg * 2 + u;
            int s = frag >> 2, ct = frag & 3;
            half8 v;
#pragma unroll
            for (int j = 0; j < 8; j++) {
                int r = s * 32 + quad * 8 + j, c = ct * 16 + qi;
                float acc = 0.f;
#pragma unroll
                for (int k = 0; k < 64; k++) acc += A[r * 64 + k] * Bs[k * 64 + c];
                v[j] = (_Float16)acc;
            }
            *(half8*)(Wf + (size_t)4096 + frag * 512 + lane * 8) = v;
        }
        return;
    }
    const float* src;
    if (g == 0) src = Wp1;
    else if (g == 2) src = Wk;
    else if (g == 3) src = Wv;
    else if (g == 4) src = Wt_;
    else if (g == 5) src = Wq1;
    else if (g == 6) src = Wk1;
    else if (g == 7) src = Wv1;
    else if (g < 16) src = Wdown + (size_t)(g - 8) * 4096;
    else if (g < 43) src = W3t + (size_t)(g - 16) * 4096;
    else if (g < 70) src = W3a + (size_t)(g - 43) * 4096;
    else src = W3b + (size_t)(g - 70) * 4096;
#pragma unroll
    for (int u = 0; u < 2; u++) {
        int frag = fg * 2 + u;
        int s = frag >> 2, ct = frag & 3;
        half8 v;
#pragma unroll
        for (int j = 0; j < 8; j++) v[j] = (_Float16)src[(s * 32 + quad * 8 + j) * 64 + ct * 16 + qi];
        *(half8*)(Wf + (size_t)g * 4096 + frag * 512 + lane * 8) = v;
    }
}

// A fp32 row -> hi/lo half8 fragments
__device__ inline void load_split8(const float* p, half8& hi, half8& lo) {
    float4 a = *(const float4*)p;
    float4 b = *(const float4*)(p + 4);
    float v[8] = {a.x, a.y, a.z, a.w, b.x, b.y, b.z, b.w};
#pragma unroll
    for (int j = 0; j < 8; j++) {
        _Float16 h = (_Float16)v[j];
        hi[j] = h;
        lo[j] = (_Float16)(v[j] - (float)h);
    }
}

// ---------------- gemm_head: 4 GEMMs in one launch (stage-1 inputs) ----------------
__global__ __launch_bounds__(256) void gemm_head(const float* __restrict__ xdec, const float* __restrict__ xenc,
                                                 const _Float16* __restrict__ Wf, float* __restrict__ xd,
                                                 _Float16* __restrict__ Qh,
                                                 _Float16* __restrict__ Kh, _Float16* __restrict__ Vt) {
    int z = blockIdx.y;
    const float* A = (z < 2) ? xdec : xenc;
    const _Float16* Bf = Wf + (size_t)z * 4096;
    int t = threadIdx.x;
    int lane = t & 63, wv = t >> 6;
    int quad = lane >> 4, qi = lane & 15;
    int row0w = blockIdx.x * 64 + wv * 16;
    half8 ah[2], al[2];
#pragma unroll
    for (int s = 0; s < 2; s++) load_split8(A + (size_t)(row0w + qi) * 64 + s * 32 + quad * 8, ah[s], al[s]);
    floatx4 C[4];
#pragma unroll
    for (int ct = 0; ct < 4; ct++) C[ct] = floatx4{0.f, 0.f, 0.f, 0.f};
#pragma unroll
    for (int ct = 0; ct < 4; ct++)
#pragma unroll
        for (int s = 0; s < 2; s++) {
            half8 b = *(const half8*)(Bf + (s * 4 + ct) * 512 + lane * 8);
            C[ct] = __builtin_amdgcn_mfma_f32_16x16x32_f16(ah[s], b, C[ct], 0, 0, 0);
            C[ct] = __builtin_amdgcn_mfma_f32_16x16x32_f16(al[s], b, C[ct], 0, 0, 0);
        }
    int orow = row0w + quad * 4;
    if (z == 0) {
#pragma unroll
        for (int ct = 0; ct < 4; ct++)
#pragma unroll
            for (int r = 0; r < 4; r++) xd[(size_t)(orow + r) * 64 + ct * 16 + qi] = C[ct][r];
    } else if (z == 1) {
#pragma unroll
        for (int ct = 0; ct < 4; ct++)
#pragma unroll
            for (int r = 0; r < 4; r++)
                Qh[(size_t)(orow + r) * 64 + ct * 16 + qi] = (_Float16)(C[ct][r] * LOG2E);
    } else if (z == 2) {
#pragma unroll
        for (int ct = 0; ct < 4; ct++)
#pragma unroll
            for (int r = 0; r < 4; r++) Kh[(size_t)(orow + r) * 64 + ct * 16 + qi] = (_Float16)C[ct][r];
    } else {
#pragma unroll
        for (int ct = 0; ct < 4; ct++) {
            half4 o;
#pragma unroll
            for (int r = 0; r < 4; r++) o[r] = (_Float16)C[ct][r];
            *(half4*)(Vt + (size_t)(ct * 16 + qi) * NPTS + orow) = o;
        }
    }
}

// ---------------- gemm_q1: fused [xd += BN(xr)] prologue + q1 = xd@Wq1 (fp16 out) ---------
__global__ __launch_bounds__(256) void gemm_q1(const float* __restrict__ xr, float* __restrict__ xd,
                                               const _Float16* __restrict__ Bf,
                                               const float* __restrict__ stats,
                                               const float* __restrict__ gamma,
                                               const float* __restrict__ beta,
                                               _Float16* __restrict__ Oh) {
    int t = threadIdx.x;
    int lane = t & 63, wv = t >> 6;
    int quad = lane >> 4, qi = lane & 15;
    int row0w = blockIdx.x * 64 + wv * 16;
    const float inv_n = 1.f / (float)NPTS;
    half8 ah[2], al[2];
#pragma unroll
    for (int s = 0; s < 2; s++) {
        size_t base = (size_t)(row0w + qi) * 64 + s * 32 + quad * 8;
        float4 xa = *(const float4*)(xr + base);
        float4 xb = *(const float4*)(xr + base + 4);
        float4 da = *(const float4*)(xd + base);
        float4 db = *(const float4*)(xd + base + 4);
        float vx[8] = {xa.x, xa.y, xa.z, xa.w, xb.x, xb.y, xb.z, xb.w};
        float vd[8] = {da.x, da.y, da.z, da.w, db.x, db.y, db.z, db.w};
        float vo[8];
#pragma unroll
        for (int j = 0; j < 8; j++) {
            int f = s * 32 + quad * 8 + j;
            float mean = stats[f] * inv_n;
            float var = stats[64 + f] * inv_n - mean * mean;
            float val = vd[j] + (vx[j] - mean) * rsqrtf(var + EPSBN) * gamma[f] + beta[f];
            vo[j] = val;
            _Float16 h = (_Float16)val;
            ah[s][j] = h;
            al[s][j] = (_Float16)(val - (float)h);
        }
        *(float4*)(xd + base) = float4{vo[0], vo[1], vo[2], vo[3]};
        *(float4*)(xd + base + 4) = float4{vo[4], vo[5], vo[6], vo[7]};
    }
    floatx4 C[4];
#pragma unroll
    for (int ct = 0; ct < 4; ct++) C[ct] = floatx4{0.f, 0.f, 0.f, 0.f};
#pragma unroll
    for (int ct = 0; ct < 4; ct++)
#pragma unroll
        for (int s = 0; s < 2; s++) {
            half8 b = *(const half8*)(Bf + (s * 4 + ct) * 512 + lane * 8);
            C[ct] = __builtin_amdgcn_mfma_f32_16x16x32_f16(ah[s], b, C[ct], 0, 0, 0);
            C[ct] = __builtin_amdgcn_mfma_f32_16x16x32_f16(al[s], b, C[ct], 0, 0, 0);
        }
    int orow = row0w + quad * 4;
#pragma unroll
    for (int ct = 0; ct < 4; ct++)
#pragma unroll
        for (int r = 0; r < 4; r++) Oh[(size_t)(orow + r) * 64 + ct * 16 + qi] = (_Float16)C[ct][r];
}

// ---------------- gemm_kv1: BN(kv) fused prologue; y=0 -> Kh1, y=1 -> Vt2 scatter ---------
__global__ __launch_bounds__(256) void gemm_kv1(const float* __restrict__ kv, const _Float16* __restrict__ Wfk,
                                                const _Float16* __restrict__ Wfv,
                                                const float* __restrict__ stats, const float* __restrict__ gamma,
                                                const float* __restrict__ beta, const int* __restrict__ unpad,
                                                _Float16* __restrict__ Kh1, _Float16* __restrict__ Vt2) {
    int y = blockIdx.y;
    int t = threadIdx.x;
    int lane = t & 63, wv = t >> 6;
    int quad = lane >> 4, qi = lane & 15;
    int row0w = blockIdx.x * 64 + wv * 16;
    const float inv_n = 1.f / (float)NPTS;
    half8 ah[2], al[2];
#pragma unroll
    for (int s = 0; s < 2; s++) {
        const float* p = kv + (size_t)(row0w + qi) * 64 + s * 32 + quad * 8;
        float4 a = *(const float4*)p;
        float4 b2 = *(const float4*)(p + 4);
        float v[8] = {a.x, a.y, a.z, a.w, b2.x, b2.y, b2.z, b2.w};
#pragma unroll
        for (int j = 0; j < 8; j++) {
            int f = s * 32 + quad * 8 + j;
            float mean = stats[f] * inv_n;
            float var = stats[64 + f] * inv_n - mean * mean;
            float val = (v[j] - mean) * rsqrtf(var + EPSBN) * gamma[f] + beta[f];
            _Float16 h = (_Float16)val;
            ah[s][j] = h;
            al[s][j] = (_Float16)(val - (float)h);
        }
    }
    const _Float16* Bf = y ? Wfv : Wfk;
    floatx4 C[4];
#pragma unroll
    for (int ct = 0; ct < 4; ct++) C[ct] = floatx4{0.f, 0.f, 0.f, 0.f};
#pragma unroll
    for (int ct = 0; ct < 4; ct++)
#pragma unroll
        for (int s = 0; s < 2; s++) {
            half8 b = *(const half8*)(Bf + (s * 4 + ct) * 512 + lane * 8);
            C[ct] = __builtin_amdgcn_mfma_f32_16x16x32_f16(ah[s], b, C[ct], 0, 0, 0);
            C[ct] = __builtin_amdgcn_mfma_f32_16x16x32_f16(al[s], b, C[ct], 0, 0, 0);
        }
    int orow = row0w + quad * 4;
    if (y == 0) {
#pragma unroll
        for (int ct = 0; ct < 4; ct++)
#pragma unroll
            for (int r = 0; r < 4; r++) Kh1[(size_t)(orow + r) * 64 + ct * 16 + qi] = (_Float16)C[ct][r];
    } else {
        int u0 = unpad[orow], u3 = unpad[orow + 3];
        int b0 = u0 / 1800, b3 = u3 / 1800;
        if (u3 == u0 + 3 && b0 == b3) {
            int p0 = u0 - b0 * 1800;
#pragma unroll
            for (int ct = 0; ct < 4; ct++) {
                half4 o;
#pragma unroll
                for (int r = 0; r < 4; r++) o[r] = (_Float16)C[ct][r];
                *(half4*)(Vt2 + ((size_t)b0 * 64 + ct * 16 + qi) * LPAD2 + p0) = o;
            }
        } else {
#pragma unroll
            for (int r = 0; r < 4; r++) {
                int u = unpad[orow + r];
                int b = u / 1800, p = u - b * 1800;
#pragma unroll
                for (int ct = 0; ct < 4; ct++)
                    Vt2[((size_t)b * 64 + ct * 16 + qi) * LPAD2 + p] = (_Float16)C[ct][r];
            }
        }
    }
}

// ---------------- gather conv, MFMA, f-split x2, depth-1 software pipeline ----------------
__global__ __launch_bounds__(256) void gconv_mfma(const _Float16* __restrict__ Xh,
                                                  const int* __restrict__ idx,
                                                  const _Float16* __restrict__ Wf,
                                                  float* __restrict__ OUT, int nk,
                                                  const float* Xadd, float* stats_out) {
    __shared__ float s_sum[64], s_ss[64];
    int t = threadIdx.x;
    int lane = t & 63, wv = t >> 6;
    int quad = lane >> 4, qi = lane & 15;
    int bx = blockIdx.x;
    int row0 = (bx >> 1) * 64 + wv * 16;
    int cb = (bx & 1) * 2;
    if (stats_out) {
        if (t < 64) {
            s_sum[t] = 0.f;
            s_ss[t] = 0.f;
        }
        __syncthreads();
    }
    floatx4 Oacc[2];
#pragma unroll
    for (int u = 0; u < 2; u++) Oacc[u] = floatx4{0.f, 0.f, 0.f, 0.f};
    const int* ip = idx + (size_t)(row0 + qi) * nk;
    int j = ip[0];
    half8 a0 = half8{0, 0, 0, 0, 0, 0, 0, 0};
    half8 a1 = half8{0, 0, 0, 0, 0, 0, 0, 0};
    if (j >= 0) {
        a0 = *(const half8*)(Xh + (size_t)j * 64 + quad * 8);
        a1 = *(const half8*)(Xh + (size_t)j * 64 + 32 + quad * 8);
    }
    for (int k = 0; k < nk; k++) {
        half8 n0 = half8{0, 0, 0, 0, 0, 0, 0, 0};
        half8 n1 = half8{0, 0, 0, 0, 0, 0, 0, 0};
        if (k + 1 < nk) {
            int jn = ip[k + 1];
            if (jn >= 0) {
                n0 = *(const half8*)(Xh + (size_t)jn * 64 + quad * 8);
                n1 = *(const half8*)(Xh + (size_t)jn * 64 + 32 + quad * 8);
            }
        }
        const _Float16* wk = Wf + (size_t)k * 4096;
#pragma unroll
        for (int u = 0; u < 2; u++) {
            int ct = cb + u;
            half8 b0 = *(const half8*)(wk + ct * 512 + lane * 8);
            half8 b1 = *(const half8*)(wk + (4 + ct) * 512 + lane * 8);
            Oacc[u] = __builtin_amdgcn_mfma_f32_16x16x32_f16(a0, b0, Oacc[u], 0, 0, 0);
            Oacc[u] = __builtin_amdgcn_mfma_f32_16x16x32_f16(a1, b1, Oacc[u], 0, 0, 0);
        }
        a0 = n0;
        a1 = n1;
    }
    int orow = row0 + quad * 4;
#pragma unroll
    for (int u = 0; u < 2; u++) {
        int ct = cb + u;
#pragma unroll
        for (int r = 0; r < 4; r++) OUT[(size_t)(orow + r) * 64 + ct * 16 + qi] = Oacc[u][r];
    }
    if (stats_out) {
#pragma unroll
        for (int u = 0; u < 2; u++) {
            int f = (cb + u) * 16 + qi;
            float ps = 0.f, pss = 0.f;
#pragma unroll
            for (int r = 0; r < 4; r++) {
                float v = Oacc[u][r];
                if (Xadd) v += Xadd[(size_t)(orow + r) * 64 + f];
                ps += v;
                pss += v * v;
            }
            atomicAdd(&s_sum[f], ps);
            atomicAdd(&s_ss[f], pss);
        }
        __syncthreads();
        if (t < 64) {
            atomicAdd(&stats_out[t], s_sum[t]);
            atomicAdd(&stats_out[64 + t], s_ss[t]);
        }
    }
}

// ---------------- gather conv with fused BN+ReLU prologue (fp32 gather), f-split x2 -------
__global__ __launch_bounds__(256) void gconv_bn_mfma(const float* __restrict__ X,
                                                     const int* __restrict__ idx,
                                                     const _Float16* __restrict__ Wf,
                                                     float* __restrict__ OUT, int nk,
                                                     const float* __restrict__ stats,
                                                     const float* __restrict__ gamma,
                                                     const float* __restrict__ beta,
                                                     const float* Xadd, float* stats_out) {
    __shared__ float s_sum[64], s_ss[64];
    int t = threadIdx.x;
    int lane = t & 63, wv = t >> 6;
    int quad = lane >> 4, qi = lane & 15;
    int bx = blockIdx.x;
    int row0 = (bx >> 1) * 64 + wv * 16;
    int cb = (bx & 1) * 2;
    if (t < 64) {
        s_sum[t] = 0.f;
        s_ss[t] = 0.f;
    }
    __syncthreads();
    const float inv_n = 1.f / (float)NPTS;
    float sc[2][8], sh[2][8];
#pragma unroll
    for (int s = 0; s < 2; s++)
#pragma unroll
        for (int jj = 0; jj < 8; jj++) {
            int f = s * 32 + quad * 8 + jj;
            float mean = stats[f] * inv_n;
            float var = stats[64 + f] * inv_n - mean * mean;
            float rs = rsqrtf(var + EPSBN) * gamma[f];
            sc[s][jj] = rs;
            sh[s][jj] = beta[f] - mean * rs;
        }
    floatx4 Oacc[2];
#pragma unroll
    for (int u = 0; u < 2; u++) Oacc[u] = floatx4{0.f, 0.f, 0.f, 0.f};
    const int* ip = idx + (size_t)(row0 + qi) * nk;
    float cur[16];
    int jvalid;
    {
        int j0 = ip[0];
        jvalid = (j0 >= 0);
        if (jvalid) {
            const float* p = X + (size_t)j0 * 64 + quad * 8;
            float4 x0 = *(const float4*)p;
            float4 x1 = *(const float4*)(p + 4);
            float4 x2 = *(const float4*)(p + 32);
            float4 x3 = *(const float4*)(p + 36);
            cur[0] = x0.x; cur[1] = x0.y; cur[2] = x0.z; cur[3] = x0.w;
            cur[4] = x1.x; cur[5] = x1.y; cur[6] = x1.z; cur[7] = x1.w;
            cur[8] = x2.x; cur[9] = x2.y; cur[10] = x2.z; cur[11] = x2.w;
            cur[12] = x3.x; cur[13] = x3.y; cur[14] = x3.z; cur[15] = x3.w;
        }
    }
    for (int k = 0; k < nk; k++) {
        half8 a0, a1;
        if (jvalid) {
#pragma unroll
            for (int e = 0; e < 8; e++) {
                a0[e] = (_Float16)fmaxf(cur[e] * sc[0][e] + sh[0][e], 0.f);
                a1[e] = (_Float16)fmaxf(cur[8 + e] * sc[1][e] + sh[1][e], 0.f);
            }
        } else {
            a0 = half8{0, 0, 0, 0, 0, 0, 0, 0};
            a1 = half8{0, 0, 0, 0, 0, 0, 0, 0};
        }
        int nvalid = 0;
        float nxt[16];
        if (k + 1 < nk) {
            int jn = ip[k + 1];
            nvalid = (jn >= 0);
            if (nvalid) {
                const float* p = X + (size_t)jn * 64 + quad * 8;
                float4 x0 = *(const float4*)p;
                float4 x1 = *(const float4*)(p + 4);
                float4 x2 = *(const float4*)(p + 32);
                float4 x3 = *(const float4*)(p + 36);
                nxt[0] = x0.x; nxt[1] = x0.y; nxt[2] = x0.z; nxt[3] = x0.w;
                nxt[4] = x1.x; nxt[5] = x1.y; nxt[6] = x1.z; nxt[7] = x1.w;
                nxt[8] = x2.x; nxt[9] = x2.y; nxt[10] = x2.z; nxt[11] = x2.w;
                nxt[12] = x3.x; nxt[13] = x3.y; nxt[14] = x3.z; nxt[15] = x3.w;
            }
        }
        const _Float16* wk = Wf + (size_t)k * 4096;
#pragma unroll
        for (int u = 0; u < 2; u++) {
            int ct = cb + u;
            half8 b0 = *(const half8*)(wk + ct * 512 + lane * 8);
            half8 b1 = *(const half8*)(wk + (4 + ct) * 512 + lane * 8);
            Oacc[u] = __builtin_amdgcn_mfma_f32_16x16x32_f16(a0, b0, Oacc[u], 0, 0, 0);
            Oacc[u] = __builtin_amdgcn_mfma_f32_16x16x32_f16(a1, b1, Oacc[u], 0, 0, 0);
        }
        jvalid = nvalid;
#pragma unroll
        for (int e = 0; e < 16; e++) cur[e] = nxt[e];
    }
    int orow = row0 + quad * 4;
#pragma unroll
    for (int u = 0; u < 2; u++) {
        int ct = cb + u;
#pragma unroll
        for (int r = 0; r < 4; r++) OUT[(size_t)(orow + r) * 64 + ct * 16 + qi] = Oacc[u][r];
    }
#pragma unroll
    for (int u = 0; u < 2; u++) {
        int f = (cb + u) * 16 + qi;
        float ps = 0.f, pss = 0.f;
#pragma unroll
        for (int r = 0; r < 4; r++) {
            float v = Oacc[u][r];
            if (Xadd) v += Xadd[(size_t)(orow + r) * 64 + f];
            ps += v;
            pss += v * v;
        }
        atomicAdd(&s_sum[f], ps);
        atomicAdd(&s_ss[f], pss);
    }
    __syncthreads();
    if (t < 64) {
        atomicAdd(&stats_out[t], s_sum[t]);
        atomicAdd(&stats_out[64 + t], s_ss[t]);
    }
}

// ---------------- bn_apply ----------------
__global__ __launch_bounds__(256) void bn_apply(const float* __restrict__ X, const float* X2,
                                                const float* R, float* OUT, _Float16* OUT16,
                                                const float* __restrict__ stats,
                                                const float* __restrict__ gamma,
                                                const float* __restrict__ beta,
                                                float* stats_out, int n, int do_relu) {
    __shared__ float sh[2][4][64];
    int t = threadIdx.x;
    int f = t & 63, g = t >> 6;
    float inv_n = 1.f / (float)n;
    float mean = stats[f] * inv_n;
    float var = stats[64 + f] * inv_n - mean * mean;
    float rstd = rsqrtf(var + EPSBN);
    float ga = gamma[f], be = beta[f];
    float s = 0.f, ss = 0.f;
    for (int r = blockIdx.x * 4 + g; r < n; r += gridDim.x * 4) {
        size_t i = (size_t)r * 64 + f;
        float v = X[i];
        if (X2) v += X2[i];
        v = (v - mean) * rstd * ga + be;
        if (R) v += R[i];
        if (do_relu) v = fmaxf(v, 0.f);
        if (OUT) OUT[i] = v;
        if (OUT16) OUT16[i] = (_Float16)v;
        s += v;
        ss += v * v;
    }
    if (stats_out) {
        sh[0][g][f] = s;
        sh[1][g][f] = ss;
        __syncthreads();
        if (g == 0) {
            s = sh[0][0][f] + sh[0][1][f] + sh[0][2][f] + sh[0][3][f];
            ss = sh[1][0][f] + sh[1][1][f] + sh[1][2][f] + sh[1][3][f];
            atomicAdd(&stats_out[f], s);
            atomicAdd(&stats_out[64 + f], ss);
        }
    }
}

// ---------------- Stage-1 flash attention: log2-domain softmax, alpha-skip ----------------
__global__ __launch_bounds__(256, 3) void flash1_mfma(const _Float16* __restrict__ Qh,
                                                      const _Float16* __restrict__ Kh,
                                                      const _Float16* __restrict__ Vt,
                                                      _Float16* __restrict__ Op,
                                                      float* __restrict__ Ms,
                                                      float* __restrict__ Ls) {
    __shared__ __align__(16) _Float16 KsF[8 * 512];
    __shared__ __align__(16) _Float16 VsF[8 * 512];
    __shared__ __align__(16) _Float16 PTF[4][2 * 1024];
    int t = threadIdx.x;
    int lane = t & 63, wv = t >> 6;
    int quad = lane >> 4, qi = lane & 15;
    int qb = blockIdx.x, sp = blockIdx.y;
    int q0w = qb * 128 + wv * 32;

    half8 qh[2][2];
#pragma unroll
    for (int sub = 0; sub < 2; sub++)
#pragma unroll
        for (int s = 0; s < 2; s++) {
            int qrow = q0w + sub * 16 + qi;
            qh[sub][s] = *(const half8*)(Qh + (size_t)qrow * 64 + s * 32 + quad * 8);
        }
    floatx4 Oacc[2][4];
#pragma unroll
    for (int sub = 0; sub < 2; sub++)
#pragma unroll
        for (int ft = 0; ft < 4; ft++) Oacc[sub][ft] = floatx4{0.f, 0.f, 0.f, 0.f};
    float m_i[2] = {-1e30f, -1e30f}, l_i[2] = {0.f, 0.f};

    for (int it = 0; it < 24; it++) {
        int k0 = sp * 1536 + it * 64;
        __syncthreads();
#pragma unroll
        for (int u = 0; u < 4; u++) {
            int frag = wv + 4 * u;
            if (frag < 8) {
                int kt = frag >> 1, s = frag & 1;
                int key = k0 + kt * 16 + qi;
                *(half8*)(KsF + frag * 512 + lane * 8) =
                    *(const half8*)(Kh + (size_t)key * 64 + s * 32 + quad * 8);
            } else {
                int fr = frag - 8;
                int ft = fr >> 1, s = fr & 1;
                int f = ft * 16 + qi;
                *(half8*)(VsF + fr * 512 + lane * 8) =
                    *(const half8*)(Vt + (size_t)f * NPTS + k0 + s * 32 + quad * 8);
            }
        }
        __syncthreads();
        half8 ka[4][2];
#pragma unroll
        for (int kt = 0; kt < 4; kt++)
#pragma unroll
            for (int s = 0; s < 2; s++) ka[kt][s] = *(const half8*)(KsF + (kt * 2 + s) * 512 + lane * 8);
        floatx4 st[2][4];
#pragma unroll
        for (int sub = 0; sub < 2; sub++)
#pragma unroll
            for (int kt = 0; kt < 4; kt++) {
                floatx4 acc = floatx4{0.f, 0.f, 0.f, 0.f};
#pragma unroll
                for (int s = 0; s < 2; s++)
                    acc = __builtin_amdgcn_mfma_f32_16x16x32_f16(ka[kt][s], qh[sub][s], acc, 0, 0, 0);
                st[sub][kt] = acc;
            }
#pragma unroll
        for (int sub = 0; sub < 2; sub++) {
            float mloc = -1e30f;
#pragma unroll
            for (int kt = 0; kt < 4; kt++)
#pragma unroll
                for (int r = 0; r < 4; r++) mloc = fmaxf(mloc, st[sub][kt][r]);
            mloc = fmaxf(mloc, __shfl_xor(mloc, 16));
            mloc = fmaxf(mloc, __shfl_xor(mloc, 32));
            float m_new = fmaxf(m_i[sub], mloc);
            float ps = 0.f;
#pragma unroll
            for (int kt = 0; kt < 4; kt++) {
                half4 pk;
#pragma unroll
                for (int r = 0; r < 4; r++) {
                    float p = EXP2F(st[sub][kt][r] - m_new);
                    ps += p;
                    pk[r] = (_Float16)p;
                }
                int s = kt >> 1;
                int qd2 = (kt & 1) * 2 + (quad >> 1);
                *(half4*)(&PTF[wv][sub * 1024 + (s * 64 + qd2 * 16 + qi) * 8 + (quad & 1) * 4]) = pk;
            }
            ps += __shfl_xor(ps, 16);
            ps += __shfl_xor(ps, 32);
            if (m_new > m_i[sub]) {
                float alpha = EXP2F(m_i[sub] - m_new);
                l_i[sub] = l_i[sub] * alpha + ps;
                m_i[sub] = m_new;
#pragma unroll
                for (int ft = 0; ft < 4; ft++) Oacc[sub][ft] *= alpha;
            } else {
                l_i[sub] += ps;
            }
        }
        half8 pb[2][2];
#pragma unroll
        for (int sub = 0; sub < 2; sub++)
#pragma unroll
            for (int s = 0; s < 2; s++)
                pb[sub][s] = *(const half8*)(&PTF[wv][sub * 1024 + (s * 64 + lane) * 8]);
#pragma unroll
        for (int ft = 0; ft < 4; ft++)
#pragma unroll
            for (int s = 0; s < 2; s++) {
                half8 v = *(const half8*)(VsF + (ft * 2 + s) * 512 + lane * 8);
                Oacc[0][ft] = __builtin_amdgcn_mfma_f32_16x16x32_f16(v, pb[0][s], Oacc[0][ft], 0, 0, 0);
                Oacc[1][ft] = __builtin_amdgcn_mfma_f32_16x16x32_f16(v, pb[1][s], Oacc[1][ft], 0, 0, 0);
            }
    }
#pragma unroll
    for (int sub = 0; sub < 2; sub++) {
#pragma unroll
        for (int ft = 0; ft < 4; ft++) {
            half4 o;
#pragma unroll
            for (int r = 0; r < 4; r++) o[r] = (_Float16)Oacc[sub][ft][r];
            *(half4*)(Op + ((size_t)sp * NPTS + q0w + sub * 16 + qi) * 64 + ft * 16 + quad * 4) = o;
        }
        if (lane < 16) {
            Ms[sp * NPTS + q0w + sub * 16 + lane] = m_i[sub];
            Ls[sp * NPTS + q0w + sub * 16 + lane] = l_i[sub];
        }
    }
}

// ---------------- merge NSPLIT partials (log2-domain m) + @Wt + fused BN-stats ------------
__global__ __launch_bounds__(256) void merge_gemm(const _Float16* __restrict__ Op,
                                                  const float* __restrict__ Ms, const float* __restrict__ Ls,
                                                  const _Float16* __restrict__ Wtf,
                                                  float* __restrict__ xr, float* __restrict__ stats_out) {
    __shared__ float w12[64][NSPLIT];
    __shared__ float Linv[64];
    __shared__ __align__(16) _Float16 Ah[64 * 72], Al[64 * 72];
    __shared__ float s_sum[64], s_ss[64];
    int t = threadIdx.x;
    int row0 = blockIdx.x * 64;
    if (t < 64) {
        int q = row0 + t;
        float m[NSPLIT], M = -1e30f;
#pragma unroll
        for (int s = 0; s < NSPLIT; s++) {
            m[s] = Ms[s * NPTS + q];
            M = fmaxf(M, m[s]);
        }
        float L = 0.f;
#pragma unroll
        for (int s = 0; s < NSPLIT; s++) {
            float w = EXP2F(m[s] - M);
            w12[t][s] = w;
            L += Ls[s * NPTS + q] * w;
        }
        Linv[t] = 1.f / L;
        s_sum[t] = 0.f;
        s_ss[t] = 0.f;
    }
    __syncthreads();
    for (int k = 0; k < 4; k++) {
        int i = t + k * 256;
        int qr = i >> 4, f4 = (i & 15) * 4;
        int q = row0 + qr;
        float acc[4] = {0.f, 0.f, 0.f, 0.f};
#pragma unroll
        for (int s = 0; s < NSPLIT; s++) {
            float w = w12[qr][s];
            half4 o = *(const half4*)(Op + ((size_t)s * NPTS + q) * 64 + f4);
#pragma unroll
            for (int c = 0; c < 4; c++) acc[c] += (float)o[c] * w;
        }
        float inv = Linv[qr];
#pragma unroll
        for (int c = 0; c < 4; c++) {
            float val = acc[c] * inv;
            _Float16 h = (_Float16)val;
            Ah[qr * 72 + f4 + c] = h;
            Al[qr * 72 + f4 + c] = (_Float16)(val - (float)h);
        }
    }
    __syncthreads();
    int lane = t & 63, wv = t >> 6;
    int quad = lane >> 4, qi = lane & 15;
    int rloc = wv * 16 + qi;
    half8 ah[2], al[2];
#pragma unroll
    for (int s = 0; s < 2; s++) {
        ah[s] = *(const half8*)(Ah + rloc * 72 + s * 32 + quad * 8);
        al[s] = *(const half8*)(Al + rloc * 72 + s * 32 + quad * 8);
    }
    floatx4 C[4];
#pragma unroll
    for (int ct = 0; ct < 4; ct++) C[ct] = floatx4{0.f, 0.f, 0.f, 0.f};
#pragma unroll
    for (int ct = 0; ct < 4; ct++)
#pragma unroll
        for (int s = 0; s < 2; s++) {
            half8 b = *(const half8*)(Wtf + (s * 4 + ct) * 512 + lane * 8);
            C[ct] = __builtin_amdgcn_mfma_f32_16x16x32_f16(ah[s], b, C[ct], 0, 0, 0);
            C[ct] = __builtin_amdgcn_mfma_f32_16x16x32_f16(al[s], b, C[ct], 0, 0, 0);
        }
    int orow = row0 + wv * 16 + quad * 4;
#pragma unroll
    for (int ct = 0; ct < 4; ct++) {
        int f = ct * 16 + qi;
        float ps = 0.f, pss = 0.f;
#pragma unroll
        for (int r = 0; r < 4; r++) {
            float v = C[ct][r];
            xr[(size_t)(orow + r) * 64 + f] = v;
            ps += v;
            pss += v * v;
        }
        atomicAdd(&s_sum[f], ps);
        atomicAdd(&s_ss[f], pss);
    }
    __syncthreads();
    if (t < 64) {
        atomicAdd(&stats_out[t], s_sum[t]);
        atomicAdd(&stats_out[64 + t], s_ss[t]);
    }
}

// ---------------- Stage-2 ragged flash attention, fp16 Q (linear domain), alpha-skip ------
__global__ __launch_bounds__(256) void flash2_mfma(const _Float16* __restrict__ Qh,
                                                   const _Float16* __restrict__ Kh,
                                                   const _Float16* __restrict__ Vt2,
                                                   const int* __restrict__ pad_idx,
                                                   const int* __restrict__ counts,
                                                   _Float16* __restrict__ O) {
    int b = blockIdx.y;
    int c = counts[b];
    int qb = blockIdx.x;
    if (qb * 64 >= c) return;
    __shared__ __align__(16) _Float16 KsF[8 * 512];
    __shared__ __align__(16) _Float16 VsF[8 * 512];
    __shared__ __align__(16) _Float16 PTF[4][2 * 512];
    int t = threadIdx.x;
    int lane = t & 63, wv = t >> 6;
    int quad = lane >> 4, qi = lane & 15;
    const int* prow = pad_idx + b * LQPAD;
    int p_q = qb * 64 + wv * 16 + qi;
    int flat_q = (p_q < LQPAD) ? prow[p_q] : -1;

    half8 qh[2];
#pragma unroll
    for (int s = 0; s < 2; s++) {
        qh[s] = (flat_q >= 0) ? *(const half8*)(Qh + (size_t)flat_q * 64 + s * 32 + quad * 8)
                              : half8{0, 0, 0, 0, 0, 0, 0, 0};
    }
    floatx4 Oacc[4];
#pragma unroll
    for (int ft = 0; ft < 4; ft++) Oacc[ft] = floatx4{0.f, 0.f, 0.f, 0.f};
    float m_i = -1e30f, l_i = 0.f;
    const _Float16* VtB = Vt2 + (size_t)b * 64 * LPAD2;

    int nt = (c + 63) >> 6;
    for (int it = 0; it < nt; it++) {
        int k0 = it * 64;
        __syncthreads();
#pragma unroll
        for (int u = 0; u < 4; u++) {
            int frag = wv + 4 * u;
            if (frag < 8) {
                int kt = frag >> 1, s = frag & 1;
                int kp = k0 + kt * 16 + qi;
                int flat = (kp < c) ? prow[kp] : -1;
                int d0 = s * 32 + quad * 8;
                half8 kvv = half8{0, 0, 0, 0, 0, 0, 0, 0};
                if (flat >= 0) kvv = *(const half8*)(Kh + (size_t)flat * 64 + d0);
                *(half8*)(KsF + frag * 512 + lane * 8) = kvv;
            } else {
                int fr = frag - 8;
                int ft = fr >> 1, s = fr & 1;
                int f = ft * 16 + qi;
                int key = k0 + s * 32 + quad * 8;
                *(half8*)(VsF + fr * 512 + lane * 8) = *(const half8*)(VtB + f * LPAD2 + key);
            }
        }
        __syncthreads();
        floatx4 st[4];
#pragma unroll
        for (int kt = 0; kt < 4; kt++) {
            floatx4 acc = floatx4{0.f, 0.f, 0.f, 0.f};
#pragma unroll
            for (int s = 0; s < 2; s++) {
                half8 a = *(const half8*)(KsF + (kt * 2 + s) * 512 + lane * 8);
                acc = __builtin_amdgcn_mfma_f32_16x16x32_f16(a, qh[s], acc, 0, 0, 0);
            }
            st[kt] = acc;
        }
        float mloc = -1e30f;
#pragma unroll
        for (int kt = 0; kt < 4; kt++)
#pragma unroll
            for (int r = 0; r < 4; r++) mloc = fmaxf(mloc, st[kt][r]);
        mloc = fmaxf(mloc, __shfl_xor(mloc, 16));
        mloc = fmaxf(mloc, __shfl_xor(mloc, 32));
        float m_new = fmaxf(m_i, mloc);
        float ps = 0.f;
#pragma unroll
        for (int kt = 0; kt < 4; kt++) {
            half4 pk;
#pragma unroll
            for (int r = 0; r < 4; r++) {
                int kpos = k0 + kt * 16 + quad * 4 + r;
                float p = (kpos < c) ? __expf(st[kt][r] - m_new) : 0.f;
                ps += p;
                pk[r] = (_Float16)p;
            }
            int s = kt >> 1;
            int qd2 = (kt & 1) * 2 + (quad >> 1);
            *(half4*)(&PTF[wv][(s * 64 + qd2 * 16 + qi) * 8 + (quad & 1) * 4]) = pk;
        }
        ps += __shfl_xor(ps, 16);
        ps += __shfl_xor(ps, 32);
        if (m_new > m_i) {
            float alpha = __expf(m_i - m_new);
            l_i = l_i * alpha + ps;
            m_i = m_new;
#pragma unroll
            for (int ft = 0; ft < 4; ft++) Oacc[ft] *= alpha;
        } else {
            l_i += ps;
        }
        half8 pb[2];
#pragma unroll
        for (int s = 0; s < 2; s++) pb[s] = *(const half8*)(&PTF[wv][(s * 64 + lane) * 8]);
#pragma unroll
        for (int ft = 0; ft < 4; ft++)
#pragma unroll
            for (int s = 0; s < 2; s++) {
                half8 a = *(const half8*)(VsF + (ft * 2 + s) * 512 + lane * 8);
                Oacc[ft] = __builtin_amdgcn_mfma_f32_16x16x32_f16(a, pb[s], Oacc[ft], 0, 0, 0);
            }
    }
    if (flat_q >= 0) {
        float inv = 1.f / l_i;
#pragma unroll
        for (int ft = 0; ft < 4; ft++) {
            half4 o;
#pragma unroll
            for (int r = 0; r < 4; r++) o[r] = (_Float16)(Oacc[ft][r] * inv);
            *(half4*)(O + (size_t)flat_q * 64 + ft * 16 + quad * 4) = o;
        }
    }
}

extern "C" void kernel_launch(void* const* d_in, const int* in_sizes, int n_in,
                              void* d_out, int out_size, void* d_ws, size_t ws_size,
                              hipStream_t stream) {
    const float* x_dec = (const float*)d_in[0];
    const float* x_enc = (const float*)d_in[1];
    const float* Wp1 = (const float*)d_in[2];
    const float* Wq = (const float*)d_in[3];
    const float* Wk = (const float*)d_in[4];
    const float* Wv = (const float*)d_in[5];
    const float* Wt_ = (const float*)d_in[6];
    const float* Wq1 = (const float*)d_in[7];
    const float* Wk1 = (const float*)d_in[8];
    const float* Wv1 = (const float*)d_in[9];
    const float* Wdown = (const float*)d_in[10];
    const float* W3t = (const float*)d_in[11];
    const float* W3a = (const float*)d_in[12];
    const float* W3b = (const float*)d_in[13];
    const float* bn_g = (const float*)d_in[14];
    const float* bn_b = (const float*)d_in[15];
    const int* nbr = (const int*)d_in[16];
    const int* kv_nbr = (const int*)d_in[17];
    const int* pad_idx = (const int*)d_in[18];
    const int* unpad_idx = (const int*)d_in[19];
    float* out = (float*)d_out;
    float* ws = (float*)d_ws;

    const int N = NPTS;
    const size_t BUF = (size_t)N * 64;
    float* xd = ws;
    float* s1 = ws + 1 * BUF;
    float* s2 = ws + 2 * BUF;
    float* s3 = ws + 3 * BUF;
    float* s4 = ws + 4 * BUF;
    float* s5 = ws + 5 * BUF;
    float* s7 = ws + 7 * BUF;
    float* s8 = ws + 8 * BUF;
    float* arena = ws + 9 * BUF;

    float* stats = arena;
    int* counts = (int*)(arena + 768);
    float* Ms = arena + 1024;
    float* Ls = Ms + (size_t)NSPLIT * NPTS;
    _Float16* WfA = (_Float16*)(Ls + (size_t)NSPLIT * NPTS);

    _Float16* Oph = (_Float16*)s1;              // 8 partials: s1..s4
    _Float16* Qh = (_Float16*)s7;
    _Float16* Kh = (_Float16*)s8;
    _Float16* Vt = Kh + BUF;
    float* xr = s8;                             // after flash1 (Kh/Vt dead)
    _Float16* Qh1 = (_Float16*)s7;
    float* kv = s1;
    _Float16* Kh1 = (_Float16*)s2;
    _Float16* Vt2 = (_Float16*)s3;
    _Float16* z2h = (_Float16*)s4;
    float* xr2 = s5;
    float* o2 = s1;                             // res-block: W3a out
    float* z2 = s3;                             // W3b out

    const _Float16* Wtf = WfA + 4 * 4096;
    const _Float16* Wq1f = WfA + 5 * 4096;
    const _Float16* Wk1f = WfA + 6 * 4096;
    const _Float16* Wv1f = WfA + 7 * 4096;
    const _Float16* Wdf = WfA + 8 * 4096;
    const _Float16* W3tf = WfA + (size_t)16 * 4096;
    const _Float16* W3af = WfA + (size_t)43 * 4096;
    const _Float16* W3bf = WfA + (size_t)70 * 4096;

    hipMemsetAsync(stats, 0, 1024 * sizeof(float), stream);

    dim3 B(256);
    int gG = N / 64;      // 192
    int gC2 = 2 * gG;     // 384: f-split x2 (all gathers)

    pack_all<<<105, B, 0, stream>>>(Wp1, Wq, Wk, Wv, Wt_, Wq1, Wk1, Wv1, Wdown, W3t, W3a, W3b,
                                    pad_idx, counts, WfA);

    gemm_head<<<dim3(gG, 4), B, 0, stream>>>(x_dec, x_enc, WfA, xd, Qh, Kh, Vt);
    flash1_mfma<<<dim3(N / 128, NSPLIT), B, 0, stream>>>(Qh, Kh, Vt, Oph, Ms, Ls);
    merge_gemm<<<gG, B, 0, stream>>>(Oph, Ms, Ls, Wtf, xr, stats + 0);
    gemm_q1<<<gG, B, 0, stream>>>(xr, xd, Wq1f, stats + 0, bn_g + 0, bn_b + 0, Qh1);

    gconv_mfma<<<gC2, B, 0, stream>>>(Qh1, kv_nbr, Wdf, kv, 8, nullptr, stats + 128);
    gemm_kv1<<<dim3(gG, 2), B, 0, stream>>>(kv, Wk1f, Wv1f, stats + 128, bn_g + 64, bn_b + 64,
                                            unpad_idx, Kh1, Vt2);
    flash2_mfma<<<dim3(LPAD2 / 64, 8), B, 0, stream>>>(Qh1, Kh1, Vt2, pad_idx, counts, z2h);
    gconv_mfma<<<gC2, B, 0, stream>>>(z2h, nbr, W3tf, xr2, 27, nullptr, stats + 256);
    bn_apply<<<256, B, 0, stream>>>(xr2, nullptr, xd, xd, nullptr, stats + 256, bn_g + 128, bn_b + 128,
                                    stats + 384, N, 0);

    gconv_bn_mfma<<<gC2, B, 0, stream>>>(xd, nbr, W3af, o2, 27, stats + 384, bn_g + 192, bn_b + 192,
                                         nullptr, stats + 512);
    gconv_bn_mfma<<<gC2, B, 0, stream>>>(o2, nbr, W3bf, z2, 27, stats + 512, bn_g + 256, bn_b + 256,
                                         xd, stats + 640);
    bn_apply<<<256, B, 0, stream>>>(xd, z2, nullptr, out, nullptr, stats + 640, bn_g + 320, bn_b + 320,
                                    nullptr, N, 1);
}